// Round 1
// baseline (251.773 us; speedup 1.0000x reference)
//
#include <hip/hip_runtime.h>
#include <hip/hip_bf16.h>
#include <stdint.h>
#include <stddef.h>

#define SEQ  8192
#define DIN  1024
#define DOUT 1024

typedef __hip_bfloat16 bf16;
typedef short bf16x8 __attribute__((ext_vector_type(8)));   // 8 bf16 = 4 VGPRs
typedef float f32x4  __attribute__((ext_vector_type(4)));

// async global->LDS, 16B per lane; dest = wave-uniform base + lane*16
#define GLOAD_LDS16(gptr, lptr)                                                     \
  __builtin_amdgcn_global_load_lds(                                                 \
      (const __attribute__((address_space(1))) void*)(gptr),                        \
      (__attribute__((address_space(3))) void*)(lptr), 16, 0, 0)

__device__ inline void store_out(float* p, float v) { *p = v; }
__device__ inline void store_out(bf16* p, float v) { *p = __float2bfloat16(v); }

// C[M x N] = A[M x K] @ B[N x K]^T   (all row-major, bf16 in, OutT out)
// m97-style: 128x128 block tile, BK=32, 256 threads = 4 waves (2x2), each wave
// a 64x64 subtile via 4x4 of mfma_f32_16x16x32_bf16.
// SPLITK: blockIdx.z selects K-chunk of length kChunk; C advanced by z*M*N.
template <typename OutT, bool SPLITK>
__global__ __launch_bounds__(256) void gemm_bt(
    const bf16* __restrict__ A, const bf16* __restrict__ B, OutT* __restrict__ C,
    int M, int N, int K, int lda, int ldb, int ldc, int kChunk)
{
  __shared__ bf16 As[128 * 32];
  __shared__ bf16 Bs[128 * 32];

  const int lane = threadIdx.x & 63;
  const int wave = threadIdx.x >> 6;
  const int m0 = blockIdx.y * 128;
  const int n0 = blockIdx.x * 128;

  int kBase = 0, kLen = K;
  if (SPLITK) {
    kBase = blockIdx.z * kChunk;
    kLen  = kChunk;
    C += (size_t)blockIdx.z * (size_t)M * (size_t)N;
  }

  // staging: lane covers 16B at LDS offset (rowgroup*1024 + lane*16)
  const int sRow = lane >> 2;        // row within 16-row group
  const int sK   = (lane & 3) * 8;   // k element offset (8 bf16 = 16B)
  const bf16* gA = A + (size_t)(m0 + sRow) * lda + kBase + sK;
  const bf16* gB = B + (size_t)(n0 + sRow) * ldb + kBase + sK;

  f32x4 acc[4][4];
#pragma unroll
  for (int i = 0; i < 4; ++i)
#pragma unroll
    for (int j = 0; j < 4; ++j)
      acc[i][j] = (f32x4){0.f, 0.f, 0.f, 0.f};

  const int wr = wave >> 1, wc = wave & 1;
  const int mW = wr * 64, nW = wc * 64;
  const int fragRow = lane & 15;
  const int k0 = (lane >> 4) * 8;

  for (int kt = 0; kt < kLen; kt += 32) {
#pragma unroll
    for (int it = 0; it < 2; ++it) {
      const int rg = it * 4 + wave;  // 16-row group 0..7
      GLOAD_LDS16(gA + (size_t)rg * 16 * lda + kt, &As[rg * 16 * 32]);
      GLOAD_LDS16(gB + (size_t)rg * 16 * ldb + kt, &Bs[rg * 16 * 32]);
    }
    asm volatile("s_waitcnt vmcnt(0)" ::: "memory");
    __syncthreads();

    bf16x8 afr[4], bfr[4];
#pragma unroll
    for (int i = 0; i < 4; ++i)
      afr[i] = *(const bf16x8*)&As[(mW + i * 16 + fragRow) * 32 + k0];
#pragma unroll
    for (int j = 0; j < 4; ++j)
      bfr[j] = *(const bf16x8*)&Bs[(nW + j * 16 + fragRow) * 32 + k0];

#pragma unroll
    for (int i = 0; i < 4; ++i)
#pragma unroll
      for (int j = 0; j < 4; ++j)
        acc[i][j] = __builtin_amdgcn_mfma_f32_16x16x32_bf16(afr[i], bfr[j], acc[i][j], 0, 0, 0);

    __syncthreads();
  }

  // epilogue: C/D layout col = lane&15, row = (lane>>4)*4 + r
  const int cCol  = lane & 15;
  const int cRow4 = (lane >> 4) * 4;
#pragma unroll
  for (int i = 0; i < 4; ++i) {
#pragma unroll
    for (int j = 0; j < 4; ++j) {
      const int row = m0 + mW + i * 16 + cRow4;
      const int col = n0 + nW + j * 16 + cCol;
#pragma unroll
      for (int r = 0; r < 4; ++r)
        store_out(&C[(size_t)(row + r) * ldc + col], acc[i][j][r]);
    }
  }
}

// cast fp32 -> bf16, optionally also emit non-transposed copy.
// in: R x C fp32. out: R x C bf16 (may be null). outT: C x R bf16.
// block (32,8), grid (C/32, R/32)
__global__ void cast_transpose(const float* __restrict__ in, bf16* __restrict__ out,
                               bf16* __restrict__ outT, int R, int C)
{
  __shared__ bf16 tile[32][33];
  const int c = blockIdx.x * 32 + threadIdx.x;
  const int r0 = blockIdx.y * 32;
#pragma unroll
  for (int i = 0; i < 4; ++i) {
    const int r = r0 + threadIdx.y + i * 8;
    const bf16 b = __float2bfloat16(in[(size_t)r * C + c]);
    if (out) out[(size_t)r * C + c] = b;
    tile[threadIdx.y + i * 8][threadIdx.x] = b;
  }
  __syncthreads();
  const int rT = r0 + threadIdx.x;
#pragma unroll
  for (int i = 0; i < 4; ++i) {
    const int cT = blockIdx.x * 32 + threadIdx.y + i * 8;
    outT[(size_t)cT * R + rT] = tile[threadIdx.x][threadIdx.y + i * 8];
  }
}

__global__ void cast_bf16(const float* __restrict__ in, bf16* __restrict__ out, int n)
{
  const int i = blockIdx.x * blockDim.x + threadIdx.x;
  if (i < n) out[i] = __float2bfloat16(in[i]);
}

__global__ void reduce_bf16(const float* __restrict__ part, bf16* __restrict__ out,
                            int n, int S)
{
  const int i = blockIdx.x * blockDim.x + threadIdx.x;
  if (i < n) {
    float s = 0.f;
    for (int z = 0; z < S; ++z) s += part[(size_t)z * n + i];
    out[i] = __float2bfloat16(s);
  }
}

extern "C" void kernel_launch(void* const* d_in, const int* in_sizes, int n_in,
                              void* d_out, int out_size, void* d_ws, size_t ws_size,
                              hipStream_t stream)
{
  const float* x  = (const float*)d_in[0];
  const float* WQ = (const float*)d_in[1];
  const float* WK = (const float*)d_in[2];
  const float* WV = (const float*)d_in[3];
  float* out = (float*)d_out;

  char* ws = (char*)d_ws;
  size_t off = 0;
  auto alloc = [&](size_t bytes) -> void* {
    void* p = ws + off;
    off += (bytes + 255) & ~(size_t)255;
    return p;
  };

  const size_t xBytes = (size_t)SEQ * DIN * sizeof(bf16);
  const size_t wBytes = (size_t)DIN * DOUT * sizeof(bf16);

  bf16* xb   = (bf16*)alloc(xBytes);   // x, bf16, 8192x1024
  bf16* xTb  = (bf16*)alloc(xBytes);   // x^T, bf16, 1024x8192
  bf16* WQb  = (bf16*)alloc(wBytes);
  bf16* WKb  = (bf16*)alloc(wBytes);
  bf16* WVTb = (bf16*)alloc(wBytes);   // WV^T
  bf16* Gb   = (bf16*)alloc(wBytes);   // x^T x (symmetric)
  bf16* P1b  = (bf16*)alloc(wBytes);   // WQ WK^T
  bf16* P2b  = (bf16*)alloc(wBytes);   // P1 G
  bf16* WpTb = (bf16*)alloc(wBytes);   // (P2 WV)^T = WV^T P2^T

  // split-K partials for G (fp32, S * 4MB); S = largest pow2 <= fit, max 8
  const size_t partOne = (size_t)DIN * DOUT * sizeof(float);
  int S = 1;
  if (ws_size > off + partOne) {
    size_t fit = (ws_size - off) / partOne;
    while (S * 2 <= (int)fit && S * 2 <= 8) S *= 2;
  }
  float* part = (float*)alloc((size_t)S * partOne);

  // 1. casts
  cast_transpose<<<dim3(DIN / 32, SEQ / 32), dim3(32, 8), 0, stream>>>(x, xb, xTb, SEQ, DIN);
  cast_bf16<<<dim3((DIN * DOUT) / 256), 256, 0, stream>>>(WQ, WQb, DIN * DOUT);
  cast_bf16<<<dim3((DIN * DOUT) / 256), 256, 0, stream>>>(WK, WKb, DIN * DOUT);
  cast_transpose<<<dim3(DOUT / 32, DIN / 32), dim3(32, 8), 0, stream>>>(WV, nullptr, WVTb, DIN, DOUT);

  // 2. G = x^T x  (A = x^T [1024x8192], B^T = x^T)  split-K
  gemm_bt<float, true><<<dim3(8, 8, S), 256, 0, stream>>>(
      xTb, xTb, part, 1024, 1024, 8192, 8192, 8192, 1024, 8192 / S);
  reduce_bf16<<<dim3((DIN * DOUT) / 256), 256, 0, stream>>>(part, Gb, DIN * DOUT, S);

  // 3. P1 = WQ @ WK^T
  gemm_bt<bf16, false><<<dim3(8, 8, 1), 256, 0, stream>>>(
      WQb, WKb, P1b, 1024, 1024, 1024, 1024, 1024, 1024, 0);
  // 4. P2 = P1 @ G   (G symmetric -> usable as B^T)
  gemm_bt<bf16, false><<<dim3(8, 8, 1), 256, 0, stream>>>(
      P1b, Gb, P2b, 1024, 1024, 1024, 1024, 1024, 1024, 0);
  // 5. W'^T = WV^T @ P2^T
  gemm_bt<bf16, false><<<dim3(8, 8, 1), 256, 0, stream>>>(
      WVTb, P2b, WpTb, 1024, 1024, 1024, 1024, 1024, 1024, 0);

  // 6. out = x @ W'  (A = xb [8192x1024], B^T = W'^T)
  gemm_bt<float, false><<<dim3(8, 64, 1), 256, 0, stream>>>(
      xb, WpTb, out, SEQ, DOUT, 1024, 1024, 1024, DOUT, 0);
}

// Round 2
// 209.818 us; speedup vs baseline: 1.2000x; 1.2000x over previous
//
#include <hip/hip_runtime.h>
#include <hip/hip_bf16.h>
#include <stdint.h>
#include <stddef.h>

#define SEQ  8192
#define DIN  1024
#define DOUT 1024

typedef __hip_bfloat16 bf16;
typedef short bf16x8 __attribute__((ext_vector_type(8)));   // 8 bf16 = 4 VGPRs
typedef float f32x4  __attribute__((ext_vector_type(4)));
typedef short s16x4  __attribute__((ext_vector_type(4)));

// async global->LDS, 16B per lane; dest = wave-uniform base + lane*16
#define GLOAD_LDS16(gptr, lptr)                                                     \
  __builtin_amdgcn_global_load_lds(                                                 \
      (const __attribute__((address_space(1))) void*)(gptr),                        \
      (__attribute__((address_space(3))) void*)(lptr), 16, 0, 0)

__device__ inline void store_out(float* p, float v) { *p = v; }
__device__ inline void store_out(bf16* p, float v) { *p = __float2bfloat16(v); }
__device__ inline short bfbits(float f) { bf16 b = __float2bfloat16(f); return *(short*)&b; }

// ---------------------------------------------------------------------------
// C[M x N] = A[M x K] @ B[N x K]^T   (row-major, bf16 in, OutT out)
// 128x128 tile, BK=32, 4 waves, each wave 64x64 via 4x4 mfma_f32_16x16x32_bf16.
// SPLITK: blockIdx.z selects K-chunk; C advanced by z*M*N.
template <typename OutT, bool SPLITK>
__global__ __launch_bounds__(256) void gemm_bt(
    const bf16* __restrict__ A, const bf16* __restrict__ B, OutT* __restrict__ C,
    int M, int N, int K, int lda, int ldb, int ldc, int kChunk)
{
  __shared__ bf16 As[128 * 32];
  __shared__ bf16 Bs[128 * 32];

  const int lane = threadIdx.x & 63;
  const int wave = threadIdx.x >> 6;
  const int m0 = blockIdx.y * 128;
  const int n0 = blockIdx.x * 128;

  int kBase = 0, kLen = K;
  if (SPLITK) {
    kBase = blockIdx.z * kChunk;
    kLen  = kChunk;
    C += (size_t)blockIdx.z * (size_t)M * (size_t)N;
  }

  const int sRow = lane >> 2;        // row within 16-row group
  const int sK   = (lane & 3) * 8;   // k element offset (8 bf16 = 16B)
  const bf16* gA = A + (size_t)(m0 + sRow) * lda + kBase + sK;
  const bf16* gB = B + (size_t)(n0 + sRow) * ldb + kBase + sK;

  f32x4 acc[4][4];
#pragma unroll
  for (int i = 0; i < 4; ++i)
#pragma unroll
    for (int j = 0; j < 4; ++j)
      acc[i][j] = (f32x4){0.f, 0.f, 0.f, 0.f};

  const int wr = wave >> 1, wc = wave & 1;
  const int mW = wr * 64, nW = wc * 64;
  const int fragRow = lane & 15;
  const int k0 = (lane >> 4) * 8;

  for (int kt = 0; kt < kLen; kt += 32) {
#pragma unroll
    for (int it = 0; it < 2; ++it) {
      const int rg = it * 4 + wave;  // 16-row group 0..7
      GLOAD_LDS16(gA + (size_t)rg * 16 * lda + kt, &As[rg * 16 * 32]);
      GLOAD_LDS16(gB + (size_t)rg * 16 * ldb + kt, &Bs[rg * 16 * 32]);
    }
    asm volatile("s_waitcnt vmcnt(0)" ::: "memory");
    __syncthreads();

    bf16x8 afr[4], bfr[4];
#pragma unroll
    for (int i = 0; i < 4; ++i)
      afr[i] = *(const bf16x8*)&As[(mW + i * 16 + fragRow) * 32 + k0];
#pragma unroll
    for (int j = 0; j < 4; ++j)
      bfr[j] = *(const bf16x8*)&Bs[(nW + j * 16 + fragRow) * 32 + k0];

#pragma unroll
    for (int i = 0; i < 4; ++i)
#pragma unroll
      for (int j = 0; j < 4; ++j)
        acc[i][j] = __builtin_amdgcn_mfma_f32_16x16x32_bf16(afr[i], bfr[j], acc[i][j], 0, 0, 0);

    __syncthreads();
  }

  const int cCol  = lane & 15;
  const int cRow4 = (lane >> 4) * 4;
#pragma unroll
  for (int i = 0; i < 4; ++i) {
#pragma unroll
    for (int j = 0; j < 4; ++j) {
      const int row = m0 + mW + i * 16 + cRow4;
      const int col = n0 + nW + j * 16 + cCol;
#pragma unroll
      for (int r = 0; r < 4; ++r)
        store_out(&C[(size_t)(row + r) * ldc + col], acc[i][j][r]);
    }
  }
}

// ---------------------------------------------------------------------------
// Small-matrix GEMM: C[M x N] = A[M x K] @ B[N x K]^T, 64x64 tile, BK=64.
// grid (N/64, M/64) -> 256 blocks for 1024^2 output = full CU coverage.
// 4 waves in 2x2; each wave 32x32 via 2x2 mfma, 2 k-steps per tile.
template <typename OutT>
__global__ __launch_bounds__(256) void gemm64(
    const bf16* __restrict__ A, const bf16* __restrict__ B, OutT* __restrict__ C,
    int K, int lda, int ldb, int ldc)
{
  __shared__ bf16 As[64 * 64];
  __shared__ bf16 Bs[64 * 64];

  const int lane = threadIdx.x & 63;
  const int wave = threadIdx.x >> 6;
  const int m0 = blockIdx.y * 64;
  const int n0 = blockIdx.x * 64;

  // staging: per issue, 256 threads cover 32 rows x 64 k (16B/lane);
  // wave w covers rows [it*32 + w*8, +8)
  const int sRow = lane >> 3;        // 0..7
  const int sK   = (lane & 7) * 8;   // 0..56
  const bf16* gA = A + (size_t)(m0 + wave * 8 + sRow) * lda + sK;
  const bf16* gB = B + (size_t)(n0 + wave * 8 + sRow) * ldb + sK;

  f32x4 acc[2][2];
#pragma unroll
  for (int i = 0; i < 2; ++i)
#pragma unroll
    for (int j = 0; j < 2; ++j)
      acc[i][j] = (f32x4){0.f, 0.f, 0.f, 0.f};

  const int wr = wave >> 1, wc = wave & 1;
  const int mW = wr * 32, nW = wc * 32;
  const int fragRow = lane & 15;
  const int k0 = (lane >> 4) * 8;

  for (int kt = 0; kt < K; kt += 64) {
#pragma unroll
    for (int it = 0; it < 2; ++it) {
      const int rb = it * 32;
      GLOAD_LDS16(gA + (size_t)rb * lda + kt, &As[(rb + wave * 8) * 64]);
      GLOAD_LDS16(gB + (size_t)rb * ldb + kt, &Bs[(rb + wave * 8) * 64]);
    }
    asm volatile("s_waitcnt vmcnt(0)" ::: "memory");
    __syncthreads();

    bf16x8 afr[2][2], bfr[2][2];  // [tile][kstep]
#pragma unroll
    for (int i = 0; i < 2; ++i)
#pragma unroll
      for (int s = 0; s < 2; ++s) {
        afr[i][s] = *(const bf16x8*)&As[(mW + i * 16 + fragRow) * 64 + s * 32 + k0];
        bfr[i][s] = *(const bf16x8*)&Bs[(nW + i * 16 + fragRow) * 64 + s * 32 + k0];
      }

#pragma unroll
    for (int s = 0; s < 2; ++s)
#pragma unroll
      for (int i = 0; i < 2; ++i)
#pragma unroll
        for (int j = 0; j < 2; ++j)
          acc[i][j] = __builtin_amdgcn_mfma_f32_16x16x32_bf16(afr[i][s], bfr[j][s], acc[i][j], 0, 0, 0);

    __syncthreads();
  }

  const int cCol  = lane & 15;
  const int cRow4 = (lane >> 4) * 4;
#pragma unroll
  for (int i = 0; i < 2; ++i) {
#pragma unroll
    for (int j = 0; j < 2; ++j) {
      const int row = m0 + mW + i * 16 + cRow4;
      const int col = n0 + nW + j * 16 + cCol;
#pragma unroll
      for (int r = 0; r < 4; ++r)
        store_out(&C[(size_t)(row + r) * ldc + col], acc[i][j][r]);
    }
  }
}

// ---------------------------------------------------------------------------
// Fused prep: one dispatch handles
//   blockIdx.y <  128 : x (8192x1024 fp32)  -> xb (bf16) + xTb (bf16 transpose)
//   128 <= y < 144    : WQ (1024x1024)      -> WQb (cast only)
//   144 <= y < 160    : WK                  -> WKb (cast only)
//   160 <= y < 176    : WV                  -> WVTb (transpose only)
// 64x64 tile, 256 threads flat. float2 reads, short2 writes (4B coalesced).
__global__ __launch_bounds__(256) void prep(
    const float* __restrict__ x, const float* __restrict__ WQ,
    const float* __restrict__ WK, const float* __restrict__ WV,
    bf16* __restrict__ xb, bf16* __restrict__ xTb,
    bf16* __restrict__ WQb, bf16* __restrict__ WKb, bf16* __restrict__ WVTb)
{
  __shared__ bf16 t[64][66];  // [col][row], pad 2 -> 4B-aligned phase-2 reads

  const int tid = threadIdx.x;
  const int gy = blockIdx.y;
  const float* in; bf16* out; bf16* outT; int r0, R;
  if (gy < 128)      { in = x;  out = xb;  outT = xTb;  r0 = gy * 64;         R = SEQ; }
  else if (gy < 144) { in = WQ; out = WQb; outT = nullptr; r0 = (gy - 128) * 64; R = DIN; }
  else if (gy < 160) { in = WK; out = WKb; outT = nullptr; r0 = (gy - 144) * 64; R = DIN; }
  else               { in = WV; out = nullptr; outT = WVTb; r0 = (gy - 160) * 64; R = DIN; }
  const int C = DIN;
  const int c0 = blockIdx.x * 64;

  // phase 1: read 64x64 fp32 tile as float2, cast, write `out`, stash transposed in LDS
#pragma unroll
  for (int i = 0; i < 8; ++i) {
    const int idx = tid + i * 256;       // 0..2047
    const int r  = idx >> 5;             // 0..63
    const int c2 = (idx & 31) * 2;       // 0..62
    const float2 f = *(const float2*)&in[(size_t)(r0 + r) * C + c0 + c2];
    const short b0 = bfbits(f.x), b1 = bfbits(f.y);
    if (out) {
      short2 p; p.x = b0; p.y = b1;
      *(short2*)&out[(size_t)(r0 + r) * C + c0 + c2] = p;
    }
    t[c2][r] = *(const bf16*)&b0;
    t[c2 + 1][r] = *(const bf16*)&b1;
  }
  if (!outT) return;
  __syncthreads();

  // phase 2: write transpose, 2 rows per thread -> 4B stores, 128B/32-lane group
#pragma unroll
  for (int i = 0; i < 8; ++i) {
    const int idx = tid + i * 256;
    const int cT = idx >> 5;             // 0..63 (local col = global row of outT)
    const int rp = (idx & 31) * 2;       // 0..62
    short2 p;
    p.x = *(const short*)&t[cT][rp];
    p.y = *(const short*)&t[cT][rp + 1];
    *(short2*)&outT[(size_t)(c0 + cT) * R + r0 + rp] = p;
  }
}

// vectorized split-K reduce: sum S fp32 partials, emit bf16. n4 = n/4.
__global__ void reduce4(const float* __restrict__ part, bf16* __restrict__ out,
                        int n4, int S)
{
  const int i = blockIdx.x * blockDim.x + threadIdx.x;
  if (i >= n4) return;
  f32x4 s = (f32x4){0.f, 0.f, 0.f, 0.f};
  for (int z = 0; z < S; ++z)
    s += *(const f32x4*)&part[(size_t)z * n4 * 4 + (size_t)i * 4];
  s16x4 o;
#pragma unroll
  for (int r = 0; r < 4; ++r) o[r] = bfbits(s[r]);
  *(s16x4*)&out[(size_t)i * 4] = o;
}

// ---------------------------------------------------------------------------
extern "C" void kernel_launch(void* const* d_in, const int* in_sizes, int n_in,
                              void* d_out, int out_size, void* d_ws, size_t ws_size,
                              hipStream_t stream)
{
  const float* x  = (const float*)d_in[0];
  const float* WQ = (const float*)d_in[1];
  const float* WK = (const float*)d_in[2];
  const float* WV = (const float*)d_in[3];
  float* out = (float*)d_out;

  char* ws = (char*)d_ws;
  size_t off = 0;
  auto alloc = [&](size_t bytes) -> void* {
    void* p = ws + off;
    off += (bytes + 255) & ~(size_t)255;
    return p;
  };

  const size_t xBytes = (size_t)SEQ * DIN * sizeof(bf16);
  const size_t wBytes = (size_t)DIN * DOUT * sizeof(bf16);

  bf16* xb   = (bf16*)alloc(xBytes);   // x, bf16, 8192x1024
  bf16* xTb  = (bf16*)alloc(xBytes);   // x^T, bf16, 1024x8192
  bf16* WQb  = (bf16*)alloc(wBytes);
  bf16* WKb  = (bf16*)alloc(wBytes);
  bf16* WVTb = (bf16*)alloc(wBytes);   // WV^T
  bf16* Gb   = (bf16*)alloc(wBytes);   // x^T x (symmetric)
  bf16* P1b  = (bf16*)alloc(wBytes);   // WQ WK^T
  bf16* P2b  = (bf16*)alloc(wBytes);   // P1 G
  bf16* WpTb = (bf16*)alloc(wBytes);   // (P2 WV)^T = WV^T P2^T

  const size_t partOne = (size_t)DIN * DOUT * sizeof(float);
  int S = 1;
  if (ws_size > off + partOne) {
    size_t fit = (ws_size - off) / partOne;
    while (S * 2 <= (int)fit && S * 2 <= 8) S *= 2;
  }
  float* part = (float*)alloc((size_t)S * partOne);

  // 1. all casts/transposes in one dispatch
  prep<<<dim3(16, 176), 256, 0, stream>>>(x, WQ, WK, WV, xb, xTb, WQb, WKb, WVTb);

  // 2. G = x^T x  (A = x^T [1024x8192], B^T = x^T)  split-K
  gemm_bt<float, true><<<dim3(8, 8, S), 256, 0, stream>>>(
      xTb, xTb, part, 1024, 1024, 8192, 8192, 8192, 1024, 8192 / S);
  reduce4<<<dim3((DIN * DOUT / 4 + 255) / 256), 256, 0, stream>>>(part, Gb, DIN * DOUT / 4, S);

  // 3. P1 = WQ @ WK^T   (256-block small GEMM)
  gemm64<bf16><<<dim3(16, 16), 256, 0, stream>>>(WQb, WKb, P1b, 1024, 1024, 1024, 1024);
  // 4. P2 = P1 @ G   (G symmetric -> usable as B^T)
  gemm64<bf16><<<dim3(16, 16), 256, 0, stream>>>(P1b, Gb, P2b, 1024, 1024, 1024, 1024);
  // 5. W'^T = WV^T @ P2^T
  gemm64<bf16><<<dim3(16, 16), 256, 0, stream>>>(WVTb, P2b, WpTb, 1024, 1024, 1024, 1024);

  // 6. out = x @ W'  (A = xb [8192x1024], B^T = W'^T)
  gemm_bt<float, false><<<dim3(8, 64, 1), 256, 0, stream>>>(
      xb, WpTb, out, SEQ, DOUT, 1024, 1024, 1024, DOUT, 0);
}

// Round 3
// 181.168 us; speedup vs baseline: 1.3897x; 1.1581x over previous
//
#include <hip/hip_runtime.h>
#include <hip/hip_bf16.h>
#include <stdint.h>
#include <stddef.h>

#define SEQ  8192
#define DIN  1024
#define DOUT 1024

typedef __hip_bfloat16 bf16;
typedef short bf16x8 __attribute__((ext_vector_type(8)));   // 8 bf16 = 4 VGPRs
typedef float f32x4  __attribute__((ext_vector_type(4)));

// async global->LDS, 16B per lane; dest = wave-uniform base + lane*16
#define GLOAD_LDS16(gptr, lptr)                                                     \
  __builtin_amdgcn_global_load_lds(                                                 \
      (const __attribute__((address_space(1))) void*)(gptr),                        \
      (__attribute__((address_space(3))) void*)(lptr), 16, 0, 0)

__device__ inline void store_out(float* p, float v) { *p = v; }
__device__ inline void store_out(bf16* p, float v) { *p = __float2bfloat16(v); }
__device__ inline short bfbits(float f) { bf16 b = __float2bfloat16(f); return *(short*)&b; }
__device__ inline float bf2f(short u) {
  unsigned v = ((unsigned)(unsigned short)u) << 16;
  return __uint_as_float(v);
}

// ---------------------------------------------------------------------------
// 128x128 tile, BK=64, XOR-swizzled LDS (2-way max bank aliasing = free).
// 4 waves in 2x2, each wave 64x64 via 4x4 mfma_f32_16x16x32_bf16, 2 k-steps.
// C[M x N] = A[M x K] @ B[N x K]^T, row-major. As/Bs: 128*64 bf16 each (16KB).
template <typename OutT>
__device__ __forceinline__ void gemm128_body(
    const bf16* __restrict__ A, const bf16* __restrict__ B, OutT* __restrict__ C,
    int bx, int by, int K, int lda, int ldb, int ldc, bf16* As, bf16* Bs)
{
  const int lane = threadIdx.x & 63;
  const int wave = threadIdx.x >> 6;
  const int m0 = by * 128, n0 = bx * 128;

  // staging: lane l -> (row r = l>>3, 16B chunk c = (l&7)^r); LDS slot = l*16B
  const int sR = lane >> 3;
  const int sC = (lane & 7) ^ sR;
  const bf16* gA = A + (size_t)(m0 + sR) * lda + sC * 8;
  const bf16* gB = B + (size_t)(n0 + sR) * ldb + sC * 8;

  f32x4 acc[4][4];
#pragma unroll
  for (int i = 0; i < 4; ++i)
#pragma unroll
    for (int j = 0; j < 4; ++j)
      acc[i][j] = (f32x4){0.f, 0.f, 0.f, 0.f};

  const int wr = wave >> 1, wc = wave & 1;
  const int mW = wr * 64, nW = wc * 64;
  const int fragRow = lane & 15;
  const int quad = lane >> 4;

  for (int kt = 0; kt < K; kt += 64) {
#pragma unroll
    for (int t = 0; t < 4; ++t) {
      const int R = (t * 4 + wave) * 8;   // 8-row group
      GLOAD_LDS16(gA + (size_t)R * lda + kt, &As[R * 64]);
      GLOAD_LDS16(gB + (size_t)R * ldb + kt, &Bs[R * 64]);
    }
    asm volatile("s_waitcnt vmcnt(0)" ::: "memory");
    __syncthreads();

#pragma unroll
    for (int s = 0; s < 2; ++s) {
      const int cw = s * 4 + quad;        // wanted 16B chunk (8 bf16)
      bf16x8 afr[4], bfr[4];
#pragma unroll
      for (int i = 0; i < 4; ++i) {
        const int ra = mW + i * 16 + fragRow;
        afr[i] = *(const bf16x8*)&As[ra * 64 + ((cw ^ (ra & 7)) << 3)];
        const int rb = nW + i * 16 + fragRow;
        bfr[i] = *(const bf16x8*)&Bs[rb * 64 + ((cw ^ (rb & 7)) << 3)];
      }
#pragma unroll
      for (int i = 0; i < 4; ++i)
#pragma unroll
        for (int j = 0; j < 4; ++j)
          acc[i][j] = __builtin_amdgcn_mfma_f32_16x16x32_bf16(afr[i], bfr[j], acc[i][j], 0, 0, 0);
    }
    __syncthreads();
  }

  const int cCol  = lane & 15;
  const int cRow4 = quad * 4;
#pragma unroll
  for (int i = 0; i < 4; ++i)
#pragma unroll
    for (int j = 0; j < 4; ++j) {
      const int row = m0 + mW + i * 16 + cRow4;
      const int col = n0 + nW + j * 16 + cCol;
#pragma unroll
      for (int r = 0; r < 4; ++r)
        store_out(&C[(size_t)(row + r) * ldc + col], acc[i][j][r]);
    }
}

// 64x64 tile, BK=64, same swizzle. 4 waves in 2x2, each 32x32 via 2x2 mfma.
// As/Bs: 64*64 bf16 each (8KB).
template <typename OutT>
__device__ __forceinline__ void gemm64_body(
    const bf16* __restrict__ A, const bf16* __restrict__ B, OutT* __restrict__ C,
    int bx, int by, int K, int lda, int ldb, int ldc, bf16* As, bf16* Bs)
{
  const int lane = threadIdx.x & 63;
  const int wave = threadIdx.x >> 6;
  const int m0 = by * 64, n0 = bx * 64;

  const int sR = lane >> 3;
  const int sC = (lane & 7) ^ sR;
  const bf16* gA = A + (size_t)(m0 + sR) * lda + sC * 8;
  const bf16* gB = B + (size_t)(n0 + sR) * ldb + sC * 8;

  f32x4 acc[2][2];
#pragma unroll
  for (int i = 0; i < 2; ++i)
#pragma unroll
    for (int j = 0; j < 2; ++j)
      acc[i][j] = (f32x4){0.f, 0.f, 0.f, 0.f};

  const int wr = wave >> 1, wc = wave & 1;
  const int mW = wr * 32, nW = wc * 32;
  const int fragRow = lane & 15;
  const int quad = lane >> 4;

  for (int kt = 0; kt < K; kt += 64) {
#pragma unroll
    for (int t = 0; t < 2; ++t) {
      const int R = (t * 4 + wave) * 8;
      GLOAD_LDS16(gA + (size_t)R * lda + kt, &As[R * 64]);
      GLOAD_LDS16(gB + (size_t)R * ldb + kt, &Bs[R * 64]);
    }
    asm volatile("s_waitcnt vmcnt(0)" ::: "memory");
    __syncthreads();

#pragma unroll
    for (int s = 0; s < 2; ++s) {
      const int cw = s * 4 + quad;
      bf16x8 afr[2], bfr[2];
#pragma unroll
      for (int i = 0; i < 2; ++i) {
        const int ra = mW + i * 16 + fragRow;
        afr[i] = *(const bf16x8*)&As[ra * 64 + ((cw ^ (ra & 7)) << 3)];
        const int rb = nW + i * 16 + fragRow;
        bfr[i] = *(const bf16x8*)&Bs[rb * 64 + ((cw ^ (rb & 7)) << 3)];
      }
#pragma unroll
      for (int i = 0; i < 2; ++i)
#pragma unroll
        for (int j = 0; j < 2; ++j)
          acc[i][j] = __builtin_amdgcn_mfma_f32_16x16x32_bf16(afr[i], bfr[j], acc[i][j], 0, 0, 0);
    }
    __syncthreads();
  }

  const int cCol  = lane & 15;
  const int cRow4 = quad * 4;
#pragma unroll
  for (int i = 0; i < 2; ++i)
#pragma unroll
    for (int j = 0; j < 2; ++j) {
      const int row = m0 + mW + i * 16 + cRow4;
      const int col = n0 + nW + j * 16 + cCol;
#pragma unroll
      for (int r = 0; r < 4; ++r)
        store_out(&C[(size_t)(row + r) * ldc + col], acc[i][j][r]);
    }
}

// ---------------------------------------------------------------------------
// merged dispatch: blocks 0..511 = split-K G partials (z = b>>6), 512..767 = P1
__global__ __launch_bounds__(256) void g_p1(
    const bf16* __restrict__ xT, const bf16* __restrict__ WQb,
    const bf16* __restrict__ WKb, bf16* __restrict__ part, bf16* __restrict__ P1)
{
  __shared__ bf16 sm[2 * 128 * 64];  // 32 KB
  const int b = blockIdx.x;
  if (b < 512) {
    const int z = b >> 6, r = b & 63;
    const bf16* Az = xT + (size_t)z * 1024;   // K-chunk offset
    gemm128_body<bf16>(Az, Az, part + (size_t)z * 1024 * 1024,
                       r & 7, r >> 3, 1024, 8192, 8192, 1024,
                       sm, sm + 128 * 64);
  } else {
    const int p = b - 512;
    gemm64_body<bf16>(WQb, WKb, P1, p & 15, p >> 4, 1024, 1024, 1024, 1024,
                      sm, sm + 64 * 64);
  }
}

__global__ __launch_bounds__(256) void gemm128_f32(
    const bf16* __restrict__ A, const bf16* __restrict__ B, float* __restrict__ C,
    int K, int lda, int ldb, int ldc)
{
  __shared__ bf16 sm[2 * 128 * 64];
  gemm128_body<float>(A, B, C, blockIdx.x, blockIdx.y, K, lda, ldb, ldc,
                      sm, sm + 128 * 64);
}

__global__ __launch_bounds__(256) void gemm64_bf(
    const bf16* __restrict__ A, const bf16* __restrict__ B, bf16* __restrict__ C,
    int K, int lda, int ldb, int ldc)
{
  __shared__ bf16 sm[2 * 64 * 64];
  gemm64_body<bf16>(A, B, C, blockIdx.x, blockIdx.y, K, lda, ldb, ldc,
                    sm, sm + 64 * 64);
}

// ---------------------------------------------------------------------------
// Fused prep (unchanged from R2): casts + transposes in one dispatch.
__global__ __launch_bounds__(256) void prep(
    const float* __restrict__ x, const float* __restrict__ WQ,
    const float* __restrict__ WK, const float* __restrict__ WV,
    bf16* __restrict__ xb, bf16* __restrict__ xTb,
    bf16* __restrict__ WQb, bf16* __restrict__ WKb, bf16* __restrict__ WVTb)
{
  __shared__ bf16 t[64][66];

  const int tid = threadIdx.x;
  const int gy = blockIdx.y;
  const float* in; bf16* out; bf16* outT; int r0, R;
  if (gy < 128)      { in = x;  out = xb;  outT = xTb;  r0 = gy * 64;         R = SEQ; }
  else if (gy < 144) { in = WQ; out = WQb; outT = nullptr; r0 = (gy - 128) * 64; R = DIN; }
  else if (gy < 160) { in = WK; out = WKb; outT = nullptr; r0 = (gy - 144) * 64; R = DIN; }
  else               { in = WV; out = nullptr; outT = WVTb; r0 = (gy - 160) * 64; R = DIN; }
  const int C = DIN;
  const int c0 = blockIdx.x * 64;

#pragma unroll
  for (int i = 0; i < 8; ++i) {
    const int idx = tid + i * 256;
    const int r  = idx >> 5;
    const int c2 = (idx & 31) * 2;
    const float2 f = *(const float2*)&in[(size_t)(r0 + r) * C + c0 + c2];
    const short b0 = bfbits(f.x), b1 = bfbits(f.y);
    if (out) {
      short2 p; p.x = b0; p.y = b1;
      *(short2*)&out[(size_t)(r0 + r) * C + c0 + c2] = p;
    }
    t[c2][r] = *(const bf16*)&b0;
    t[c2 + 1][r] = *(const bf16*)&b1;
  }
  if (!outT) return;
  __syncthreads();

#pragma unroll
  for (int i = 0; i < 8; ++i) {
    const int idx = tid + i * 256;
    const int cT = idx >> 5;
    const int rp = (idx & 31) * 2;
    short2 p;
    p.x = *(const short*)&t[cT][rp];
    p.y = *(const short*)&t[cT][rp + 1];
    *(short2*)&outT[(size_t)(c0 + cT) * R + r0 + rp] = p;
  }
}

// sum S bf16 partials (stride 1M elems) -> bf16; 8 elems (16B) per thread
__global__ void reduce8(const bf16* __restrict__ part, bf16* __restrict__ out, int S)
{
  const int i = blockIdx.x * blockDim.x + threadIdx.x;   // 0..131071
  const size_t base = (size_t)i * 8;
  float s[8] = {0.f, 0.f, 0.f, 0.f, 0.f, 0.f, 0.f, 0.f};
  for (int z = 0; z < S; ++z) {
    bf16x8 v = *(const bf16x8*)&part[((size_t)z << 20) + base];
#pragma unroll
    for (int r = 0; r < 8; ++r) s[r] += bf2f(v[r]);
  }
  bf16x8 o;
#pragma unroll
  for (int r = 0; r < 8; ++r) o[r] = bfbits(s[r]);
  *(bf16x8*)&out[base] = o;
}

// ---------------------------------------------------------------------------
extern "C" void kernel_launch(void* const* d_in, const int* in_sizes, int n_in,
                              void* d_out, int out_size, void* d_ws, size_t ws_size,
                              hipStream_t stream)
{
  const float* x  = (const float*)d_in[0];
  const float* WQ = (const float*)d_in[1];
  const float* WK = (const float*)d_in[2];
  const float* WV = (const float*)d_in[3];
  float* out = (float*)d_out;

  char* ws = (char*)d_ws;
  size_t off = 0;
  auto alloc = [&](size_t bytes) -> void* {
    void* p = ws + off;
    off += (bytes + 255) & ~(size_t)255;
    return p;
  };

  const size_t xBytes = (size_t)SEQ * DIN * sizeof(bf16);
  const size_t wBytes = (size_t)DIN * DOUT * sizeof(bf16);
  const int S = 8;

  bf16* xb   = (bf16*)alloc(xBytes);   // x, bf16
  bf16* xTb  = (bf16*)alloc(xBytes);   // x^T, bf16
  bf16* WQb  = (bf16*)alloc(wBytes);
  bf16* WKb  = (bf16*)alloc(wBytes);
  bf16* WVTb = (bf16*)alloc(wBytes);   // WV^T
  bf16* Gb   = (bf16*)alloc(wBytes);   // x^T x (symmetric)
  bf16* P1b  = (bf16*)alloc(wBytes);   // WQ WK^T
  bf16* Utb  = (bf16*)alloc(wBytes);   // (G WV)^T = WV^T G
  bf16* WpTb = (bf16*)alloc(wBytes);   // W'^T = Ut P1^T
  bf16* part = (bf16*)alloc((size_t)S * wBytes);  // split-K partials, bf16

  // 1. all casts/transposes
  prep<<<dim3(16, 176), 256, 0, stream>>>(x, WQ, WK, WV, xb, xTb, WQb, WKb, WVTb);

  // 2. G split-K partials (512 blocks) || P1 = WQ WK^T (256 blocks)
  g_p1<<<dim3(768), 256, 0, stream>>>(xTb, WQb, WKb, part, P1b);

  // 3. G = sum partials
  reduce8<<<dim3(512), 256, 0, stream>>>(part, Gb, S);

  // 4. Ut = WV^T G  (= (G WV)^T, G symmetric)
  gemm64_bf<<<dim3(16, 16), 256, 0, stream>>>(WVTb, Gb, Utb, 1024, 1024, 1024, 1024);
  // 5. W'^T = Ut P1^T
  gemm64_bf<<<dim3(16, 16), 256, 0, stream>>>(Utb, P1b, WpTb, 1024, 1024, 1024, 1024);

  // 6. out = x W'  (A = xb, B^T = W'^T)
  gemm128_f32<<<dim3(8, 64), 256, 0, stream>>>(xb, WpTb, out, 1024, 1024, 1024, DOUT);
}

// Round 4
// 163.056 us; speedup vs baseline: 1.5441x; 1.1111x over previous
//
#include <hip/hip_runtime.h>
#include <hip/hip_bf16.h>
#include <stdint.h>
#include <stddef.h>

#define SEQ  8192
#define DIN  1024
#define DOUT 1024

typedef __hip_bfloat16 bf16;
typedef short bf16x8 __attribute__((ext_vector_type(8)));   // 8 bf16 = 4 VGPRs
typedef float f32x4  __attribute__((ext_vector_type(4)));

// async global->LDS, 16B per lane; dest = wave-uniform base + lane*16
#define GLOAD_LDS16(gptr, lptr)                                                     \
  __builtin_amdgcn_global_load_lds(                                                 \
      (const __attribute__((address_space(1))) void*)(gptr),                        \
      (__attribute__((address_space(3))) void*)(lptr), 16, 0, 0)

__device__ inline void store_out(float* p, float v) { *p = v; }
__device__ inline void store_out(bf16* p, float v) { *p = __float2bfloat16(v); }
__device__ inline short bfbits(float f) { bf16 b = __float2bfloat16(f); return *(short*)&b; }
__device__ inline float bf2f(short u) {
  unsigned v = ((unsigned)(unsigned short)u) << 16;
  return __uint_as_float(v);
}

// ---------------------------------------------------------------------------
// 128x128 tile, BK=64, XOR-swizzled LDS, DOUBLE-BUFFERED (prefetch 1 tile,
// vmcnt(8) one-iter-late wait, raw s_barrier -> no full drain per iter).
// As/Bs each hold 2 buffers of 128*64 bf16 (16 KB) -> 64 KB total LDS.
template <typename OutT>
__device__ __forceinline__ void gemm128_body(
    const bf16* __restrict__ A, const bf16* __restrict__ B, OutT* __restrict__ C,
    int bx, int by, int K, int lda, int ldb, int ldc, bf16* As, bf16* Bs)
{
  const int lane = threadIdx.x & 63;
  const int wave = threadIdx.x >> 6;
  const int m0 = by * 128, n0 = bx * 128;

  const int sR = lane >> 3;
  const int sC = (lane & 7) ^ sR;       // XOR swizzle -> conflict-free b128 reads
  const bf16* gA = A + (size_t)(m0 + sR) * lda + sC * 8;
  const bf16* gB = B + (size_t)(n0 + sR) * ldb + sC * 8;

  f32x4 acc[4][4];
#pragma unroll
  for (int i = 0; i < 4; ++i)
#pragma unroll
    for (int j = 0; j < 4; ++j)
      acc[i][j] = (f32x4){0.f, 0.f, 0.f, 0.f};

  const int wr = wave >> 1, wc = wave & 1;
  const int mW = wr * 64, nW = wc * 64;
  const int fragRow = lane & 15;
  const int quad = lane >> 4;

  auto stage = [&](int kt, int buf) {
    bf16* dA = As + buf * (128 * 64);
    bf16* dB = Bs + buf * (128 * 64);
#pragma unroll
    for (int t = 0; t < 4; ++t) {
      const int R = (t * 4 + wave) * 8;
      GLOAD_LDS16(gA + (size_t)R * lda + kt, &dA[R * 64]);
      GLOAD_LDS16(gB + (size_t)R * ldb + kt, &dB[R * 64]);
    }
  };

  const int nT = K >> 6;
  stage(0, 0);
  for (int kt = 0; kt < nT; ++kt) {
    const int buf = kt & 1;
    if (kt + 1 < nT) {
      stage((kt + 1) << 6, buf ^ 1);
      asm volatile("s_waitcnt vmcnt(8)" ::: "memory");   // wait tile kt only
    } else {
      asm volatile("s_waitcnt vmcnt(0)" ::: "memory");
    }
    asm volatile("s_barrier" ::: "memory");

    const bf16* Ab = As + buf * (128 * 64);
    const bf16* Bb = Bs + buf * (128 * 64);
    bf16x8 afr[2][4], bfr[2][4];
#pragma unroll
    for (int s = 0; s < 2; ++s) {
      const int cw = s * 4 + quad;
#pragma unroll
      for (int i = 0; i < 4; ++i) {
        const int ra = mW + i * 16 + fragRow;
        afr[s][i] = *(const bf16x8*)&Ab[ra * 64 + ((cw ^ (ra & 7)) << 3)];
        const int rb = nW + i * 16 + fragRow;
        bfr[s][i] = *(const bf16x8*)&Bb[rb * 64 + ((cw ^ (rb & 7)) << 3)];
      }
    }
    asm volatile("s_waitcnt lgkmcnt(0)" ::: "memory");   // frags in regs
    asm volatile("s_barrier" ::: "memory");              // buf safe to refill

#pragma unroll
    for (int s = 0; s < 2; ++s)
#pragma unroll
      for (int i = 0; i < 4; ++i)
#pragma unroll
        for (int j = 0; j < 4; ++j)
          acc[i][j] = __builtin_amdgcn_mfma_f32_16x16x32_bf16(afr[s][i], bfr[s][j], acc[i][j], 0, 0, 0);
  }

  const int cCol  = lane & 15;
  const int cRow4 = quad * 4;
#pragma unroll
  for (int i = 0; i < 4; ++i)
#pragma unroll
    for (int j = 0; j < 4; ++j) {
      const int row = m0 + mW + i * 16 + cRow4;
      const int col = n0 + nW + j * 16 + cCol;
#pragma unroll
      for (int r = 0; r < 4; ++r)
        store_out(&C[(size_t)(row + r) * ldc + col], acc[i][j][r]);
    }
}

// 64x64 tile, BK=64, same swizzle, double-buffered. As/Bs each 2*64*64 bf16.
template <typename OutT>
__device__ __forceinline__ void gemm64_body(
    const bf16* __restrict__ A, const bf16* __restrict__ B, OutT* __restrict__ C,
    int bx, int by, int K, int lda, int ldb, int ldc, bf16* As, bf16* Bs)
{
  const int lane = threadIdx.x & 63;
  const int wave = threadIdx.x >> 6;
  const int m0 = by * 64, n0 = bx * 64;

  const int sR = lane >> 3;
  const int sC = (lane & 7) ^ sR;
  const bf16* gA = A + (size_t)(m0 + sR) * lda + sC * 8;
  const bf16* gB = B + (size_t)(n0 + sR) * ldb + sC * 8;

  f32x4 acc[2][2];
#pragma unroll
  for (int i = 0; i < 2; ++i)
#pragma unroll
    for (int j = 0; j < 2; ++j)
      acc[i][j] = (f32x4){0.f, 0.f, 0.f, 0.f};

  const int wr = wave >> 1, wc = wave & 1;
  const int mW = wr * 32, nW = wc * 32;
  const int fragRow = lane & 15;
  const int quad = lane >> 4;

  auto stage = [&](int kt, int buf) {
    bf16* dA = As + buf * (64 * 64);
    bf16* dB = Bs + buf * (64 * 64);
#pragma unroll
    for (int t = 0; t < 2; ++t) {
      const int R = (t * 4 + wave) * 8;
      GLOAD_LDS16(gA + (size_t)R * lda + kt, &dA[R * 64]);
      GLOAD_LDS16(gB + (size_t)R * ldb + kt, &dB[R * 64]);
    }
  };

  const int nT = K >> 6;
  stage(0, 0);
  for (int kt = 0; kt < nT; ++kt) {
    const int buf = kt & 1;
    if (kt + 1 < nT) {
      stage((kt + 1) << 6, buf ^ 1);
      asm volatile("s_waitcnt vmcnt(4)" ::: "memory");
    } else {
      asm volatile("s_waitcnt vmcnt(0)" ::: "memory");
    }
    asm volatile("s_barrier" ::: "memory");

    const bf16* Ab = As + buf * (64 * 64);
    const bf16* Bb = Bs + buf * (64 * 64);
    bf16x8 afr[2][2], bfr[2][2];
#pragma unroll
    for (int s = 0; s < 2; ++s) {
      const int cw = s * 4 + quad;
#pragma unroll
      for (int i = 0; i < 2; ++i) {
        const int ra = mW + i * 16 + fragRow;
        afr[s][i] = *(const bf16x8*)&Ab[ra * 64 + ((cw ^ (ra & 7)) << 3)];
        const int rb = nW + i * 16 + fragRow;
        bfr[s][i] = *(const bf16x8*)&Bb[rb * 64 + ((cw ^ (rb & 7)) << 3)];
      }
    }
    asm volatile("s_waitcnt lgkmcnt(0)" ::: "memory");
    asm volatile("s_barrier" ::: "memory");

#pragma unroll
    for (int s = 0; s < 2; ++s)
#pragma unroll
      for (int i = 0; i < 2; ++i)
#pragma unroll
        for (int j = 0; j < 2; ++j)
          acc[i][j] = __builtin_amdgcn_mfma_f32_16x16x32_bf16(afr[s][i], bfr[s][j], acc[i][j], 0, 0, 0);
  }

  const int cCol  = lane & 15;
  const int cRow4 = quad * 4;
#pragma unroll
  for (int i = 0; i < 2; ++i)
#pragma unroll
    for (int j = 0; j < 2; ++j) {
      const int row = m0 + mW + i * 16 + cRow4;
      const int col = n0 + nW + j * 16 + cCol;
#pragma unroll
      for (int r = 0; r < 4; ++r)
        store_out(&C[(size_t)(row + r) * ldc + col], acc[i][j][r]);
    }
}

// ---------------------------------------------------------------------------
// merged: blocks 0..511 = split-K G partials (z = b&7 -> one K-chunk per XCD,
// 2 MB xTb slice L2-resident, 16x reuse), 512..767 = P1 = WQ WK^T.
__global__ __launch_bounds__(256) void g_p1(
    const bf16* __restrict__ xT, const bf16* __restrict__ WQb,
    const bf16* __restrict__ WKb, bf16* __restrict__ part, bf16* __restrict__ P1)
{
  __shared__ bf16 sm[4 * 128 * 64];  // 64 KB
  const int b = blockIdx.x;
  if (b < 512) {
    const int z = b & 7;      // XCD round-robin -> chunk z stays on one XCD
    const int r = b >> 3;     // 64 output tiles
    const bf16* Az = xT + (size_t)z * 1024;
    gemm128_body<bf16>(Az, Az, part + ((size_t)z << 20),
                       r & 7, r >> 3, 1024, 8192, 8192, 1024,
                       sm, sm + 2 * 128 * 64);
  } else {
    const int p = b - 512;
    gemm64_body<bf16>(WQb, WKb, P1, p & 15, p >> 4, 1024, 1024, 1024, 1024,
                      sm, sm + 2 * 64 * 64);
  }
}

// final GEMM: XCD-swizzled so each XCD owns 8 consecutive by (A rows 2 MB,
// L2-resident, 8x reuse). grid 512 = 8 xcd * 8 by * 8 bx.
__global__ __launch_bounds__(256) void gemm128_f32(
    const bf16* __restrict__ A, const bf16* __restrict__ B, float* __restrict__ C,
    int K, int lda, int ldb, int ldc)
{
  __shared__ bf16 sm[4 * 128 * 64];
  const int id = blockIdx.x;
  const int by = ((id & 7) << 3) | ((id >> 3) & 7);
  const int bx = id >> 6;
  gemm128_body<float>(A, B, C, bx, by, K, lda, ldb, ldc, sm, sm + 2 * 128 * 64);
}

__global__ __launch_bounds__(256) void gemm64_bf(
    const bf16* __restrict__ A, const bf16* __restrict__ B, bf16* __restrict__ C,
    int K, int lda, int ldb, int ldc)
{
  __shared__ bf16 sm[4 * 64 * 64];
  gemm64_body<bf16>(A, B, C, blockIdx.x, blockIdx.y, K, lda, ldb, ldc,
                    sm, sm + 2 * 64 * 64);
}

// ---------------------------------------------------------------------------
// prep_all, one dispatch:
//   blocks 0..5119    : flat cast (x->xb 4096 blocks, WQ->WQb 512, WK->WKb 512)
//                       float4 x2 reads, bf16x8 16B stores, fully coalesced
//   blocks 5120..6143 : transpose x -> xTb, 128x64 tiles (256B rd / 256B wr)
//   blocks 6144..6271 : transpose WV -> WVTb
__global__ __launch_bounds__(256) void prep_all(
    const float* __restrict__ x, const float* __restrict__ WQ,
    const float* __restrict__ WK, const float* __restrict__ WV,
    bf16* __restrict__ xb, bf16* __restrict__ xTb,
    bf16* __restrict__ WQb, bf16* __restrict__ WKb, bf16* __restrict__ WVTb)
{
  __shared__ bf16 t[128][68];   // row stride 68: b64-aligned, low conflict
  int b = blockIdx.x;

  if (b < 5120) {
    const size_t i = ((size_t)b * 256 + threadIdx.x) * 8;
    const float* src; bf16* dst;
    if (i < 8388608)      { src = x  + i;           dst = xb  + i; }
    else if (i < 9437184) { src = WQ + (i - 8388608); dst = WQb + (i - 8388608); }
    else                  { src = WK + (i - 9437184); dst = WKb + (i - 9437184); }
    const float4 f0 = *(const float4*)src;
    const float4 f1 = *(const float4*)(src + 4);
    bf16x8 o;
    o[0] = bfbits(f0.x); o[1] = bfbits(f0.y); o[2] = bfbits(f0.z); o[3] = bfbits(f0.w);
    o[4] = bfbits(f1.x); o[5] = bfbits(f1.y); o[6] = bfbits(f1.z); o[7] = bfbits(f1.w);
    *(bf16x8*)dst = o;
    return;
  }

  b -= 5120;
  const float* src; bf16* dst; int ldOut, tr, tc;
  if (b < 1024) { src = x;  dst = xTb;  ldOut = SEQ; tr = b >> 4; tc = b & 15; }
  else { b -= 1024; src = WV; dst = WVTb; ldOut = DIN; tr = b >> 4; tc = b & 15; }
  const int r0 = tr * 128, c0 = tc * 64;

  // phase 1: 128 rows x 64 cols fp32, float4 reads -> short4 LDS writes
#pragma unroll
  for (int p = 0; p < 8; ++p) {
    const int q = threadIdx.x + p * 256;   // float4 id, 0..2047
    const int r = q >> 4, c4 = (q & 15) * 4;
    const float4 f = *(const float4*)&src[(size_t)(r0 + r) * DIN + c0 + c4];
    short4 s4;
    s4.x = bfbits(f.x); s4.y = bfbits(f.y); s4.z = bfbits(f.z); s4.w = bfbits(f.w);
    *(short4*)&t[r][c4] = s4;
  }
  __syncthreads();

  // phase 2: 64 outT-rows x 256 B, bf16x8 16B stores (16 lanes per row)
#pragma unroll
  for (int p = 0; p < 4; ++p) {
    const int h = threadIdx.x + p * 256;   // 0..1023
    const int c = h >> 4, seg = h & 15;
    bf16x8 o;
#pragma unroll
    for (int i = 0; i < 8; ++i)
      o[i] = *(const short*)&t[seg * 8 + i][c];
    *(bf16x8*)&dst[(size_t)(c0 + c) * ldOut + r0 + seg * 8] = o;
  }
}

// sum 8 bf16 partials (stride 1M elems) -> bf16; 8 elems (16B) per thread
__global__ void reduce8(const bf16* __restrict__ part, bf16* __restrict__ out, int S)
{
  const int i = blockIdx.x * blockDim.x + threadIdx.x;
  const size_t base = (size_t)i * 8;
  float s[8] = {0.f, 0.f, 0.f, 0.f, 0.f, 0.f, 0.f, 0.f};
  for (int z = 0; z < S; ++z) {
    bf16x8 v = *(const bf16x8*)&part[((size_t)z << 20) + base];
#pragma unroll
    for (int r = 0; r < 8; ++r) s[r] += bf2f(v[r]);
  }
  bf16x8 o;
#pragma unroll
  for (int r = 0; r < 8; ++r) o[r] = bfbits(s[r]);
  *(bf16x8*)&out[base] = o;
}

// ---------------------------------------------------------------------------
extern "C" void kernel_launch(void* const* d_in, const int* in_sizes, int n_in,
                              void* d_out, int out_size, void* d_ws, size_t ws_size,
                              hipStream_t stream)
{
  const float* x  = (const float*)d_in[0];
  const float* WQ = (const float*)d_in[1];
  const float* WK = (const float*)d_in[2];
  const float* WV = (const float*)d_in[3];
  float* out = (float*)d_out;

  char* ws = (char*)d_ws;
  size_t off = 0;
  auto alloc = [&](size_t bytes) -> void* {
    void* p = ws + off;
    off += (bytes + 255) & ~(size_t)255;
    return p;
  };

  const size_t xBytes = (size_t)SEQ * DIN * sizeof(bf16);
  const size_t wBytes = (size_t)DIN * DOUT * sizeof(bf16);
  const int S = 8;

  bf16* xb   = (bf16*)alloc(xBytes);   // x, bf16
  bf16* xTb  = (bf16*)alloc(xBytes);   // x^T, bf16
  bf16* WQb  = (bf16*)alloc(wBytes);
  bf16* WKb  = (bf16*)alloc(wBytes);
  bf16* WVTb = (bf16*)alloc(wBytes);   // WV^T
  bf16* Gb   = (bf16*)alloc(wBytes);   // x^T x (symmetric)
  bf16* P1b  = (bf16*)alloc(wBytes);   // WQ WK^T
  bf16* Utb  = (bf16*)alloc(wBytes);   // (G WV)^T = WV^T G
  bf16* WpTb = (bf16*)alloc(wBytes);   // W'^T = Ut P1^T
  bf16* part = (bf16*)alloc((size_t)S * wBytes);  // split-K partials

  // 1. casts + transposes, one dispatch
  prep_all<<<dim3(6272), 256, 0, stream>>>(x, WQ, WK, WV, xb, xTb, WQb, WKb, WVTb);

  // 2. G split-K partials (XCD-localized) || P1 = WQ WK^T
  g_p1<<<dim3(768), 256, 0, stream>>>(xTb, WQb, WKb, part, P1b);

  // 3. G = sum partials
  reduce8<<<dim3(512), 256, 0, stream>>>(part, Gb, S);

  // 4. Ut = WV^T G  (= (G WV)^T, G symmetric)
  gemm64_bf<<<dim3(16, 16), 256, 0, stream>>>(WVTb, Gb, Utb, 1024, 1024, 1024, 1024);
  // 5. W'^T = Ut P1^T
  gemm64_bf<<<dim3(16, 16), 256, 0, stream>>>(Utb, P1b, WpTb, 1024, 1024, 1024, 1024);

  // 6. out = x W'  (XCD-swizzled)
  gemm128_f32<<<dim3(512), 256, 0, stream>>>(xb, WpTb, out, 1024, 1024, 1024, DOUT);
}